// Round 3
// baseline (963.119 us; speedup 1.0000x reference)
//
#include <hip/hip_runtime.h>
#include <hip/hip_fp16.h>

#define DI __device__ __forceinline__

constexpr int TH = 64, TW = 64;   // output tile
constexpr int P1 = 100;           // xtT pitch in halfs (96 + 4 pad, keeps 8B align)
constexpr int P2 = 68;            // hb pitch in halfs (64 + 4 pad, keeps 8B align)
constexpr float kC1 = 1.0e-4f;    // (0.01*1)^2
constexpr float kC2 = 9.0e-4f;    // (0.03*1)^2
constexpr float kALPHA = 0.025f;

DI float rcp_fast(float v) { return __builtin_amdgcn_rcpf(v); }

DI void ld4h(const __half* __restrict__ s, float& f0, float& f1, float& f2, float& f3) {
  uint2 u = *reinterpret_cast<const uint2*>(s);
  __half2 a = *reinterpret_cast<__half2*>(&u.x);
  __half2 b = *reinterpret_cast<__half2*>(&u.y);
  f0 = __low2float(a); f1 = __high2float(a);
  f2 = __low2float(b); f3 = __high2float(b);
}

DI void st4h(__half* __restrict__ d, float a0, float a1, float a2, float a3) {
  __half2 p = __floats2half2_rn(a0, a1);
  __half2 q = __floats2half2_rn(a2, a3);
  uint2 u;
  u.x = *reinterpret_cast<unsigned*>(&p);
  u.y = *reinterpret_cast<unsigned*>(&q);
  *reinterpret_cast<uint2*>(d) = u;
}

// ---- horizontal conv as a STREAMING pass over the transposed tile ----
// Output h(r,c) = sum_j wk[j] * src[r][c+16-R+j], r in [0,96), c in [0,64).
// Each thread: 4 cols (stream dim) x 4 rows (b64-contiguous dim).
// No windowed arrays -> every alloca is constant-indexed -> stays in VGPRs.
// MODE 0: h0=conv(v), h1=conv(v^2) from s0.
// MODE 1: h0=conv(x*y).   MODE 2: h0=conv(x*y), h1=conv(|x-y|).
template<int R, int MODE>
DI void hstream(const __half* __restrict__ s0, const __half* __restrict__ s1,
                __half* __restrict__ h0, __half* __restrict__ h1,
                const float* __restrict__ wk, int tid) {
  constexpr int K = 2 * R + 1;
  for (int s = tid; s < 384; s += 256) {   // 16 colgrp x 24 rowgrp patches
    const int cg = s & 15, rg = s >> 4;
    const int c0 = cg << 2, r0 = rg << 2;
    float a[4][4], b[4][4];
#pragma unroll
    for (int i = 0; i < 4; ++i)
#pragma unroll
      for (int k = 0; k < 4; ++k) { a[i][k] = 0.f; b[i][k] = 0.f; }
    for (int t = 0; t < K + 3; ++t) {
      const int u = c0 + 16 - R + t;       // in [0,96)
      float x0, x1, x2, x3;
      ld4h(s0 + u * P1 + r0, x0, x1, x2, x3);
      float p0, p1, p2, p3, d0, d1, d2, d3;
      if (MODE == 0) {                      // hoist squares out of cc loop
        p0 = x0 * x0; p1 = x1 * x1; p2 = x2 * x2; p3 = x3 * x3;
      } else {
        float y0, y1, y2, y3;
        ld4h(s1 + u * P1 + r0, y0, y1, y2, y3);
        p0 = x0 * y0; p1 = x1 * y1; p2 = x2 * y2; p3 = x3 * y3;
        if (MODE == 2) {
          d0 = fabsf(x0 - y0); d1 = fabsf(x1 - y1);
          d2 = fabsf(x2 - y2); d3 = fabsf(x3 - y3);
        }
      }
#pragma unroll
      for (int cc = 0; cc < 4; ++cc) {
        const int j = t - cc;
        if (j >= 0 && j < K) {             // lane-uniform scalar branch
          const float w = wk[j];
          if (MODE == 0) {
            a[cc][0] = fmaf(w, x0, a[cc][0]); a[cc][1] = fmaf(w, x1, a[cc][1]);
            a[cc][2] = fmaf(w, x2, a[cc][2]); a[cc][3] = fmaf(w, x3, a[cc][3]);
            b[cc][0] = fmaf(w, p0, b[cc][0]); b[cc][1] = fmaf(w, p1, b[cc][1]);
            b[cc][2] = fmaf(w, p2, b[cc][2]); b[cc][3] = fmaf(w, p3, b[cc][3]);
          } else {
            a[cc][0] = fmaf(w, p0, a[cc][0]); a[cc][1] = fmaf(w, p1, a[cc][1]);
            a[cc][2] = fmaf(w, p2, a[cc][2]); a[cc][3] = fmaf(w, p3, a[cc][3]);
            if (MODE == 2) {
              b[cc][0] = fmaf(w, d0, b[cc][0]); b[cc][1] = fmaf(w, d1, b[cc][1]);
              b[cc][2] = fmaf(w, d2, b[cc][2]); b[cc][3] = fmaf(w, d3, b[cc][3]);
            }
          }
        }
      }
    }
#pragma unroll
    for (int i = 0; i < 4; ++i) {          // write back transposed: hb[row][col]
      st4h(h0 + (r0 + i) * P2 + c0, a[0][i], a[1][i], a[2][i], a[3][i]);
      if (MODE == 0 || MODE == 2)
        st4h(h1 + (r0 + i) * P2 + c0, b[0][i], b[1][i], b[2][i], b[3][i]);
    }
  }
}

// ---- vertical conv: stream hb rows; 4 rows x 4 cols per thread ----
template<int R, bool TWO>
DI void vstream(const __half* __restrict__ h0, const __half* __restrict__ h1,
                const float* __restrict__ wk, int tid,
                float* __restrict__ acc0, float* __restrict__ acc1) {
  constexpr int K = 2 * R + 1;
  const int cg = tid & 15, rg = tid >> 4;
  const int c0 = cg << 2, r0 = rg << 2;
  for (int t = 0; t < K + 3; ++t) {
    const int lr = r0 + (16 - R) + t;
    float x0, x1, x2, x3;
    ld4h(h0 + lr * P2 + c0, x0, x1, x2, x3);
    float y0 = 0.f, y1 = 0.f, y2 = 0.f, y3 = 0.f;
    if (TWO) ld4h(h1 + lr * P2 + c0, y0, y1, y2, y3);
#pragma unroll
    for (int rr = 0; rr < 4; ++rr) {
      const int j = t - rr;
      if (j >= 0 && j < K) {
        const float w = wk[j];
        acc0[rr * 4 + 0] = fmaf(w, x0, acc0[rr * 4 + 0]);
        acc0[rr * 4 + 1] = fmaf(w, x1, acc0[rr * 4 + 1]);
        acc0[rr * 4 + 2] = fmaf(w, x2, acc0[rr * 4 + 2]);
        acc0[rr * 4 + 3] = fmaf(w, x3, acc0[rr * 4 + 3]);
        if (TWO) {
          acc1[rr * 4 + 0] = fmaf(w, y0, acc1[rr * 4 + 0]);
          acc1[rr * 4 + 1] = fmaf(w, y1, acc1[rr * 4 + 1]);
          acc1[rr * 4 + 2] = fmaf(w, y2, acc1[rr * 4 + 2]);
          acc1[rr * 4 + 3] = fmaf(w, y3, acc1[rr * 4 + 3]);
        }
      }
    }
  }
}

template<int R, bool LAST>
DI void do_sigma(int sidx, const float* __restrict__ w1d,
                 const __half* __restrict__ xtT, const __half* __restrict__ ytT,
                 __half* __restrict__ hb0, __half* __restrict__ hb1,
                 float* __restrict__ PIcs, float* __restrict__ lM,
                 float* __restrict__ gl1, int tid) {
  const float* wk = w1d + sidx * 33 + (16 - R);
  float mux[16], muy[16], es2[16], exy[16];   // es2 = E[x^2]+E[y^2] merged
#pragma unroll
  for (int i = 0; i < 16; ++i) { mux[i] = 0; muy[i] = 0; es2[i] = 0; exy[i] = 0; }
  hstream<R, 0>(xtT, xtT, hb0, hb1, wk, tid);
  __syncthreads();
  vstream<R, true>(hb0, hb1, wk, tid, mux, es2);
  __syncthreads();
  hstream<R, 0>(ytT, ytT, hb0, hb1, wk, tid);
  __syncthreads();
  vstream<R, true>(hb0, hb1, wk, tid, muy, es2);
  __syncthreads();
  hstream<R, (LAST ? 2 : 1)>(xtT, ytT, hb0, hb1, wk, tid);
  __syncthreads();
  vstream<R, LAST>(hb0, hb1, wk, tid, exy, gl1);  // gl1 accumulated in-place
  __syncthreads();
#pragma unroll
  for (int i = 0; i < 16; ++i) {
    float m2x = mux[i] * mux[i];
    float m2y = muy[i] * muy[i];
    float mxy = mux[i] * muy[i];
    float sxy = exy[i] - mxy;
    float s2  = es2[i] - m2x - m2y;
    float cs = fmaf(2.f, sxy, kC2) * rcp_fast(s2 + kC2);
    PIcs[i] *= cs;
    if (LAST) {
      float l = fmaf(2.f, mxy, kC1) * rcp_fast(m2x + m2y + kC1);
      lM[i] *= l;
    }
  }
}

// ---- extract 1D separable kernels: g[j] = mask[16][j] / sqrt(mask[16][16]) ----
__global__ void prep_k(const float* __restrict__ gm, float* __restrict__ w1d) {
  int t = threadIdx.x;
  if (t < 165) {
    int s = t / 33, j = t % 33;
    const float* m = gm + (3 * s) * (33 * 33);
    float g16 = sqrtf(m[16 * 33 + 16]);
    w1d[t] = m[16 * 33 + j] / g16;
  }
}

__global__ __attribute__((amdgpu_flat_work_group_size(256, 256),
                          amdgpu_waves_per_eu(2, 2)))
void msloss_k(const float* __restrict__ x, const float* __restrict__ y,
              const float* __restrict__ w1d, float* __restrict__ out) {
  __shared__ __half xtT[96 * P1];   // transposed: xtT[col][row]
  __shared__ __half ytT[96 * P1];
  __shared__ __half hb0[96 * P2];   // hb[row][col]
  __shared__ __half hb1[96 * P2];
  __shared__ float red[4];
  const int tid = threadIdx.x;
  const int ox = blockIdx.x * TW, oy = blockIdx.y * TH;
  const int b = blockIdx.z;

  float PIcs[16], lM[16], gl1[16];
#pragma unroll
  for (int i = 0; i < 16; ++i) { PIcs[i] = 1.f; lM[i] = 1.f; gl1[i] = 0.f; }

  for (int c = 0; c < 3; ++c) {
    const float* xp = x + (size_t)(b * 3 + c) * (512 * 512);
    const float* yp = y + (size_t)(b * 3 + c) * (512 * 512);
    // stage 96x96 fp32 -> fp16 TRANSPOSED, zero halo
    for (int t = 0; t < 9; ++t) {
      int idx = t * 256 + tid;            // 2304 slots = 96 rows x 24 colquads
      int row = idx / 24, c4 = idx % 24;
      int gy = oy + row - 16, gx = ox + c4 * 4 - 16;
      bool ok = ((unsigned)gy < 512u) && ((unsigned)gx < 512u);
      float4 xv = make_float4(0.f, 0.f, 0.f, 0.f);
      float4 yv = make_float4(0.f, 0.f, 0.f, 0.f);
      if (ok) {
        xv = *reinterpret_cast<const float4*>(xp + gy * 512 + gx);
        yv = *reinterpret_cast<const float4*>(yp + gy * 512 + gx);
      }
      float xs[4] = {xv.x, xv.y, xv.z, xv.w};
      float ys[4] = {yv.x, yv.y, yv.z, yv.w};
#pragma unroll
      for (int i = 0; i < 4; ++i) {
        xtT[(c4 * 4 + i) * P1 + row] = __float2half_rn(xs[i]);
        ytT[(c4 * 4 + i) * P1 + row] = __float2half_rn(ys[i]);
      }
    }
    __syncthreads();
    do_sigma<4,  false>(0, w1d, xtT, ytT, hb0, hb1, PIcs, lM, gl1, tid);
    do_sigma<6,  false>(1, w1d, xtT, ytT, hb0, hb1, PIcs, lM, gl1, tid);
    do_sigma<12, false>(2, w1d, xtT, ytT, hb0, hb1, PIcs, lM, gl1, tid);
    do_sigma<16, false>(3, w1d, xtT, ytT, hb0, hb1, PIcs, lM, gl1, tid);
    do_sigma<16, true >(4, w1d, xtT, ytT, hb0, hb1, PIcs, lM, gl1, tid);
    // do_sigma ends with __syncthreads(): safe to restage next channel
  }

  float s = 0.f;
#pragma unroll
  for (int i = 0; i < 16; ++i)
    s += kALPHA * (1.f - lM[i] * PIcs[i]) + ((1.f - kALPHA) / 3.f) * gl1[i];
#pragma unroll
  for (int off = 32; off > 0; off >>= 1) s += __shfl_down(s, off);
  if ((tid & 63) == 0) red[tid >> 6] = s;
  __syncthreads();
  if (tid == 0)
    atomicAdd(out, (red[0] + red[1] + red[2] + red[3]) *
                       (200.0f / (8.0f * 512.0f * 512.0f)));
}

extern "C" void kernel_launch(void* const* d_in, const int* in_sizes, int n_in,
                              void* d_out, int out_size, void* d_ws, size_t ws_size,
                              hipStream_t stream) {
  const float* x = (const float*)d_in[0];
  const float* y = (const float*)d_in[1];
  const float* gm = (const float*)d_in[2];
  float* out = (float*)d_out;
  float* w1d = (float*)d_ws;  // 165 floats of 1D kernels

  hipMemsetAsync(d_out, 0, out_size * sizeof(float), stream);
  prep_k<<<1, 256, 0, stream>>>(gm, w1d);
  msloss_k<<<dim3(8, 8, 8), 256, 0, stream>>>(x, y, w1d, out);
}

// Round 4
// 923.969 us; speedup vs baseline: 1.0424x; 1.0424x over previous
//
#include <hip/hip_runtime.h>
#include <hip/hip_fp16.h>

#define DI __device__ __forceinline__

constexpr int TH = 64, TW = 64;   // output tile
constexpr int P1 = 98;            // xtT pitch (halfs): 49 dwords -> spread banks
constexpr int P2 = 66;            // hb pitch (halfs): 33 dwords -> conflict-free
constexpr float kC1 = 1.0e-4f;    // (0.01*1)^2
constexpr float kC2 = 9.0e-4f;    // (0.03*1)^2
constexpr float kALPHA = 0.025f;

DI float rcp_fast(float v) { return __builtin_amdgcn_rcpf(v); }

// 4 halfs via two u32 LDS reads (pitches are 4B- but not 8B-aligned)
DI void ld4h(const __half* __restrict__ s, float& f0, float& f1, float& f2, float& f3) {
  unsigned ua = *reinterpret_cast<const unsigned*>(s);
  unsigned ub = *reinterpret_cast<const unsigned*>(s + 2);
  __half2 a = *reinterpret_cast<__half2*>(&ua);
  __half2 b = *reinterpret_cast<__half2*>(&ub);
  f0 = __low2float(a); f1 = __high2float(a);
  f2 = __low2float(b); f3 = __high2float(b);
}

DI void st2h(__half* __restrict__ d, float a0, float a1) {
  __half2 p = __floats2half2_rn(a0, a1);
  *reinterpret_cast<unsigned*>(d) = *reinterpret_cast<unsigned*>(&p);
}

// ---- horizontal conv, streaming over transposed tile ----
// h(r,c) = sum_j wk[j]*src[r][c+16-R+j], r in [0,96), c in [0,64).
// Patch = 2 output cols (stream dim) x 4 rows: 768 patches = 3/thread (even).
// MODE 0: h0=conv(v), h1=conv(v^2).  MODE 1: h0=conv(x*y).
// MODE 2: h0=conv(x*y), h1=conv(|x-y|).
template<int R, int MODE>
DI void hstream(const __half* __restrict__ s0, const __half* __restrict__ s1,
                __half* __restrict__ h0, __half* __restrict__ h1,
                const float* __restrict__ wk, int tid) {
  constexpr int K = 2 * R + 1;
  for (int pp = 0; pp < 3; ++pp) {
    const int s = tid + pp * 256;          // 0..767
    const int cg = s & 31, rg = s >> 5;    // 32 colgroups x 24 rowgroups
    const int c0 = cg * 2, r0 = rg * 4;
    float a[2][4], b[2][4];
#pragma unroll
    for (int i = 0; i < 2; ++i)
#pragma unroll
      for (int k = 0; k < 4; ++k) { a[i][k] = 0.f; b[i][k] = 0.f; }
#pragma unroll 2
    for (int t = 0; t < K + 1; ++t) {
      const int u = c0 + 16 - R + t;       // in [0,96)
      float x0, x1, x2, x3;
      ld4h(s0 + u * P1 + r0, x0, x1, x2, x3);
      float p0, p1, p2, p3, d0, d1, d2, d3;
      if (MODE == 0) {
        p0 = x0 * x0; p1 = x1 * x1; p2 = x2 * x2; p3 = x3 * x3;
      } else {
        float y0, y1, y2, y3;
        ld4h(s1 + u * P1 + r0, y0, y1, y2, y3);
        p0 = x0 * y0; p1 = x1 * y1; p2 = x2 * y2; p3 = x3 * y3;
        if (MODE == 2) {
          d0 = fabsf(x0 - y0); d1 = fabsf(x1 - y1);
          d2 = fabsf(x2 - y2); d3 = fabsf(x3 - y3);
        }
      }
#pragma unroll
      for (int cc = 0; cc < 2; ++cc) {
        const int j = t - cc;
        if (j >= 0 && j < K) {             // lane-uniform (SALU) branch
          const float w = wk[j];
          if (MODE == 0) {
            a[cc][0] = fmaf(w, x0, a[cc][0]); a[cc][1] = fmaf(w, x1, a[cc][1]);
            a[cc][2] = fmaf(w, x2, a[cc][2]); a[cc][3] = fmaf(w, x3, a[cc][3]);
            b[cc][0] = fmaf(w, p0, b[cc][0]); b[cc][1] = fmaf(w, p1, b[cc][1]);
            b[cc][2] = fmaf(w, p2, b[cc][2]); b[cc][3] = fmaf(w, p3, b[cc][3]);
          } else {
            a[cc][0] = fmaf(w, p0, a[cc][0]); a[cc][1] = fmaf(w, p1, a[cc][1]);
            a[cc][2] = fmaf(w, p2, a[cc][2]); a[cc][3] = fmaf(w, p3, a[cc][3]);
            if (MODE == 2) {
              b[cc][0] = fmaf(w, d0, b[cc][0]); b[cc][1] = fmaf(w, d1, b[cc][1]);
              b[cc][2] = fmaf(w, d2, b[cc][2]); b[cc][3] = fmaf(w, d3, b[cc][3]);
            }
          }
        }
      }
    }
#pragma unroll
    for (int i = 0; i < 4; ++i) {          // hb[row][col]; bank = (r0+i+cg)%32
      st2h(h0 + (r0 + i) * P2 + c0, a[0][i], a[1][i]);
      if (MODE == 0 || MODE == 2)
        st2h(h1 + (r0 + i) * P2 + c0, b[0][i], b[1][i]);
    }
  }
}

// ---- vertical conv: stream hb rows; 4 rows x 4 cols per thread ----
template<int R, bool TWO>
DI void vstream(const __half* __restrict__ h0, const __half* __restrict__ h1,
                const float* __restrict__ wk, int tid,
                float* __restrict__ acc0, float* __restrict__ acc1) {
  constexpr int K = 2 * R + 1;
  const int cg = tid & 15, rg = tid >> 4;
  const int c0 = cg << 2, r0 = rg << 2;
#pragma unroll 2
  for (int t = 0; t < K + 3; ++t) {
    const int lr = r0 + (16 - R) + t;
    float x0, x1, x2, x3;
    ld4h(h0 + lr * P2 + c0, x0, x1, x2, x3);
    float y0 = 0.f, y1 = 0.f, y2 = 0.f, y3 = 0.f;
    if (TWO) ld4h(h1 + lr * P2 + c0, y0, y1, y2, y3);
#pragma unroll
    for (int rr = 0; rr < 4; ++rr) {
      const int j = t - rr;
      if (j >= 0 && j < K) {
        const float w = wk[j];
        acc0[rr * 4 + 0] = fmaf(w, x0, acc0[rr * 4 + 0]);
        acc0[rr * 4 + 1] = fmaf(w, x1, acc0[rr * 4 + 1]);
        acc0[rr * 4 + 2] = fmaf(w, x2, acc0[rr * 4 + 2]);
        acc0[rr * 4 + 3] = fmaf(w, x3, acc0[rr * 4 + 3]);
        if (TWO) {
          acc1[rr * 4 + 0] = fmaf(w, y0, acc1[rr * 4 + 0]);
          acc1[rr * 4 + 1] = fmaf(w, y1, acc1[rr * 4 + 1]);
          acc1[rr * 4 + 2] = fmaf(w, y2, acc1[rr * 4 + 2]);
          acc1[rr * 4 + 3] = fmaf(w, y3, acc1[rr * 4 + 3]);
        }
      }
    }
  }
}

// Phase-pipelined per-sigma: peak live per-sigma state is 48 regs (phase 1-2:
// mux,muy,s2) then 32 (mxy,rden) -- fits the 128-VGPR budget with persistent
// PIcs+gl1 (32) and ~40 working regs. R0-R3 spilled ~830 MB of scratch because
// the old layout kept 64+48 accumulators live across every phase.
template<int R, bool LAST>
DI void do_sigma(int sidx, const float* __restrict__ w1d,
                 const __half* __restrict__ xtT, const __half* __restrict__ ytT,
                 __half* __restrict__ hb0, __half* __restrict__ hb1,
                 float* __restrict__ PIcs, float* __restrict__ gl1, int tid) {
  const float* wk = w1d + sidx * 33 + (16 - R);
  float mux[16], muy[16], s2[16];          // s2 = E[x^2]+E[y^2] merged
#pragma unroll
  for (int i = 0; i < 16; ++i) { mux[i] = 0.f; s2[i] = 0.f; }
  hstream<R, 0>(xtT, xtT, hb0, hb1, wk, tid);
  __syncthreads();
  vstream<R, true>(hb0, hb1, wk, tid, mux, s2);
  __syncthreads();
  hstream<R, 0>(ytT, ytT, hb0, hb1, wk, tid);
  __syncthreads();
#pragma unroll
  for (int i = 0; i < 16; ++i) muy[i] = 0.f;
  vstream<R, true>(hb0, hb1, wk, tid, muy, s2);
  __syncthreads();
  // fold means into (mxy, rden) NOW so mux/muy/s2 die before phase 3
  float mxy[16], rden[16];
#pragma unroll
  for (int i = 0; i < 16; ++i) {
    float m2x = mux[i] * mux[i];
    float m2y = muy[i] * muy[i];
    mxy[i] = mux[i] * muy[i];
    rden[i] = rcp_fast(s2[i] - m2x - m2y + kC2);
    if (LAST)   // luminance factor folded straight into PIcs (lM eliminated)
      PIcs[i] *= fmaf(2.f, mxy[i], kC1) * rcp_fast(m2x + m2y + kC1);
  }
  hstream<R, (LAST ? 2 : 1)>(xtT, ytT, hb0, hb1, wk, tid);
  __syncthreads();
  float exy[16];
#pragma unroll
  for (int i = 0; i < 16; ++i) exy[i] = 0.f;
  vstream<R, LAST>(hb0, hb1, wk, tid, exy, gl1);  // gl1 accumulated in-place
  __syncthreads();
#pragma unroll
  for (int i = 0; i < 16; ++i)
    PIcs[i] *= fmaf(2.f, exy[i] - mxy[i], kC2) * rden[i];
}

// ---- extract 1D separable kernels: g[j] = mask[16][j] / sqrt(mask[16][16]) ----
__global__ void prep_k(const float* __restrict__ gm, float* __restrict__ w1d) {
  int t = threadIdx.x;
  if (t < 165) {
    int s = t / 33, j = t % 33;
    const float* m = gm + (3 * s) * (33 * 33);
    float g16 = sqrtf(m[16 * 33 + 16]);
    w1d[t] = m[16 * 33 + j] / g16;
  }
}

__global__ __attribute__((amdgpu_flat_work_group_size(256, 256),
                          amdgpu_waves_per_eu(2, 2)))
void msloss_k(const float* __restrict__ x, const float* __restrict__ y,
              const float* __restrict__ w1d, float* __restrict__ out) {
  __shared__ __half xtT[96 * P1];   // transposed: xtT[col][row]
  __shared__ __half ytT[96 * P1];
  __shared__ __half hb0[96 * P2];   // hb[row][col]
  __shared__ __half hb1[96 * P2];
  __shared__ float red[4];
  const int tid = threadIdx.x;
  const int ox = blockIdx.x * TW, oy = blockIdx.y * TH;
  const int b = blockIdx.z;

  float PIcs[16], gl1[16];
#pragma unroll
  for (int i = 0; i < 16; ++i) { PIcs[i] = 1.f; gl1[i] = 0.f; }

  for (int c = 0; c < 3; ++c) {
    const float* xp = x + (size_t)(b * 3 + c) * (512 * 512);
    const float* yp = y + (size_t)(b * 3 + c) * (512 * 512);
    // stage 96x96 fp32 -> fp16 TRANSPOSED, zero halo
    for (int t = 0; t < 9; ++t) {
      int idx = t * 256 + tid;            // 2304 slots = 96 rows x 24 colquads
      int row = idx / 24, c4 = idx % 24;
      int gy = oy + row - 16, gx = ox + c4 * 4 - 16;
      bool ok = ((unsigned)gy < 512u) && ((unsigned)gx < 512u);
      float4 xv = make_float4(0.f, 0.f, 0.f, 0.f);
      float4 yv = make_float4(0.f, 0.f, 0.f, 0.f);
      if (ok) {
        xv = *reinterpret_cast<const float4*>(xp + gy * 512 + gx);
        yv = *reinterpret_cast<const float4*>(yp + gy * 512 + gx);
      }
      float xs[4] = {xv.x, xv.y, xv.z, xv.w};
      float ys[4] = {yv.x, yv.y, yv.z, yv.w};
#pragma unroll
      for (int i = 0; i < 4; ++i) {
        xtT[(c4 * 4 + i) * P1 + row] = __float2half_rn(xs[i]);
        ytT[(c4 * 4 + i) * P1 + row] = __float2half_rn(ys[i]);
      }
    }
    __syncthreads();
    do_sigma<4,  false>(0, w1d, xtT, ytT, hb0, hb1, PIcs, gl1, tid);
    do_sigma<6,  false>(1, w1d, xtT, ytT, hb0, hb1, PIcs, gl1, tid);
    do_sigma<12, false>(2, w1d, xtT, ytT, hb0, hb1, PIcs, gl1, tid);
    do_sigma<16, false>(3, w1d, xtT, ytT, hb0, hb1, PIcs, gl1, tid);
    do_sigma<16, true >(4, w1d, xtT, ytT, hb0, hb1, PIcs, gl1, tid);
    // do_sigma ends with __syncthreads(): safe to restage next channel
  }

  float s = 0.f;
#pragma unroll
  for (int i = 0; i < 16; ++i)
    s += kALPHA * (1.f - PIcs[i]) + ((1.f - kALPHA) / 3.f) * gl1[i];
#pragma unroll
  for (int off = 32; off > 0; off >>= 1) s += __shfl_down(s, off);
  if ((tid & 63) == 0) red[tid >> 6] = s;
  __syncthreads();
  if (tid == 0)
    atomicAdd(out, (red[0] + red[1] + red[2] + red[3]) *
                       (200.0f / (8.0f * 512.0f * 512.0f)));
}

extern "C" void kernel_launch(void* const* d_in, const int* in_sizes, int n_in,
                              void* d_out, int out_size, void* d_ws, size_t ws_size,
                              hipStream_t stream) {
  const float* x = (const float*)d_in[0];
  const float* y = (const float*)d_in[1];
  const float* gm = (const float*)d_in[2];
  float* out = (float*)d_out;
  float* w1d = (float*)d_ws;  // 165 floats of 1D kernels

  hipMemsetAsync(d_out, 0, out_size * sizeof(float), stream);
  prep_k<<<1, 256, 0, stream>>>(gm, w1d);
  msloss_k<<<dim3(8, 8, 8), 256, 0, stream>>>(x, y, w1d, out);
}

// Round 5
// 787.717 us; speedup vs baseline: 1.2227x; 1.1730x over previous
//
#include <hip/hip_runtime.h>
#include <hip/hip_fp16.h>

#define DI __device__ __forceinline__

constexpr int TH = 64, TW = 64;   // output tile
constexpr int P1 = 98;            // xtT pitch (halfs), col-major [col][row]
constexpr int P2 = 66;            // hb pitch (halfs), [row][col]; 33 dwords
constexpr float kC1 = 1.0e-4f;    // (0.01*1)^2
constexpr float kC2 = 9.0e-4f;    // (0.03*1)^2
constexpr float kALPHA = 0.025f;

DI float rcp_fast(float v) { return __builtin_amdgcn_rcpf(v); }

DI void ld2h(const __half* __restrict__ s, float& f0, float& f1) {
  unsigned u = *reinterpret_cast<const unsigned*>(s);
  __half2 h = *reinterpret_cast<__half2*>(&u);
  f0 = __low2float(h); f1 = __high2float(h);
}

DI void st2h(__half* __restrict__ d, float a0, float a1) {
  __half2 p = __floats2half2_rn(a0, a1);
  *reinterpret_cast<unsigned*>(d) = *reinterpret_cast<unsigned*>(&p);
}

// ---- horizontal conv over transposed tile; patch = 2 cols x 2 rows ----
// Only rows [16-R, 80+R) are produced (what vstream consumes).
// MODE 0: h0=conv(v), h1=conv(v^2).  MODE 1: h0=conv(x*y).
// MODE 2: h0=conv(x*y), h1=conv(|x-y|).
template<int R, int MODE>
DI void hstream(const __half* __restrict__ s0, const __half* __restrict__ s1,
                __half* __restrict__ h0, __half* __restrict__ h1,
                const float* __restrict__ wk, int tid) {
  constexpr int K = 2 * R + 1;
  constexpr int NP = 32 * (32 + R);        // 32 colpairs x (32+R) rowpairs
  for (int s = tid; s < NP; s += 512) {
    const int cg = s & 31, rg = s >> 5;
    const int c0 = cg * 2, r0 = (16 - R) + rg * 2;
    float a00 = 0, a01 = 0, a10 = 0, a11 = 0;
    float b00 = 0, b01 = 0, b10 = 0, b11 = 0;
#pragma unroll 2
    for (int t = 0; t < K + 1; ++t) {
      const int u = c0 + 16 - R + t;       // in [0,96)
      float x0, x1;
      ld2h(s0 + u * P1 + r0, x0, x1);
      float p0, p1, d0 = 0.f, d1 = 0.f;
      if (MODE == 0) {
        p0 = x0 * x0; p1 = x1 * x1;
      } else {
        float y0, y1;
        ld2h(s1 + u * P1 + r0, y0, y1);
        p0 = x0 * y0; p1 = x1 * y1;
        if (MODE == 2) { d0 = fabsf(x0 - y0); d1 = fabsf(x1 - y1); }
      }
      if (t < K) {                          // col c0, tap j = t (uniform branch)
        const float w = wk[t];
        if (MODE == 0) {
          a00 = fmaf(w, x0, a00); a01 = fmaf(w, x1, a01);
          b00 = fmaf(w, p0, b00); b01 = fmaf(w, p1, b01);
        } else {
          a00 = fmaf(w, p0, a00); a01 = fmaf(w, p1, a01);
          if (MODE == 2) { b00 = fmaf(w, d0, b00); b01 = fmaf(w, d1, b01); }
        }
      }
      if (t >= 1) {                         // col c0+1, tap j = t-1
        const float w = wk[t - 1];
        if (MODE == 0) {
          a10 = fmaf(w, x0, a10); a11 = fmaf(w, x1, a11);
          b10 = fmaf(w, p0, b10); b11 = fmaf(w, p1, b11);
        } else {
          a10 = fmaf(w, p0, a10); a11 = fmaf(w, p1, a11);
          if (MODE == 2) { b10 = fmaf(w, d0, b10); b11 = fmaf(w, d1, b11); }
        }
      }
    }
    st2h(h0 + (r0 + 0) * P2 + c0, a00, a10);
    st2h(h0 + (r0 + 1) * P2 + c0, a01, a11);
    if (MODE == 0 || MODE == 2) {
      st2h(h1 + (r0 + 0) * P2 + c0, b00, b10);
      st2h(h1 + (r0 + 1) * P2 + c0, b01, b11);
    }
  }
}

// ---- vertical conv: patch = 4 rows x 2 cols, exactly 1 patch/thread ----
// read addr dword = lr*33 + cg: cg spans all 32 banks per half-wave -> <=2-way
template<int R, bool TWO>
DI void vstream(const __half* __restrict__ h0, const __half* __restrict__ h1,
                const float* __restrict__ wk, int tid,
                float* __restrict__ acc0, float* __restrict__ acc1) {
  constexpr int K = 2 * R + 1;
  const int cg = tid & 31, rq = tid >> 5;
  const int c0 = cg * 2, r0 = rq * 4;
#pragma unroll 2
  for (int t = 0; t < K + 3; ++t) {
    const int lr = r0 + (16 - R) + t;
    float x0, x1;
    ld2h(h0 + lr * P2 + c0, x0, x1);
    float y0 = 0.f, y1 = 0.f;
    if (TWO) ld2h(h1 + lr * P2 + c0, y0, y1);
#pragma unroll
    for (int rr = 0; rr < 4; ++rr) {
      const int j = t - rr;
      if (j >= 0 && j < K) {
        const float w = wk[j];
        acc0[rr * 2 + 0] = fmaf(w, x0, acc0[rr * 2 + 0]);
        acc0[rr * 2 + 1] = fmaf(w, x1, acc0[rr * 2 + 1]);
        if (TWO) {
          acc1[rr * 2 + 0] = fmaf(w, y0, acc1[rr * 2 + 0]);
          acc1[rr * 2 + 1] = fmaf(w, y1, acc1[rr * 2 + 1]);
        }
      }
    }
  }
}

// Phase-pipelined per-sigma; all per-thread arrays are 8 floats (8 outputs).
// Peak live ~70 regs -> fits the 128-VGPR budget (hard cap observed R0-R4).
template<int R, bool LAST>
DI void do_sigma(int sidx, const float* __restrict__ w1d,
                 const __half* __restrict__ xtT, const __half* __restrict__ ytT,
                 __half* __restrict__ hb0, __half* __restrict__ hb1,
                 float* __restrict__ PIcs, float* __restrict__ gl1, int tid) {
  const float* wk = w1d + sidx * 33 + (16 - R);
  float mux[8], muy[8], s2[8];             // s2 = E[x^2]+E[y^2] merged
#pragma unroll
  for (int i = 0; i < 8; ++i) { mux[i] = 0.f; s2[i] = 0.f; }
  hstream<R, 0>(xtT, xtT, hb0, hb1, wk, tid);
  __syncthreads();
  vstream<R, true>(hb0, hb1, wk, tid, mux, s2);
  __syncthreads();
  hstream<R, 0>(ytT, ytT, hb0, hb1, wk, tid);
  __syncthreads();
#pragma unroll
  for (int i = 0; i < 8; ++i) muy[i] = 0.f;
  vstream<R, true>(hb0, hb1, wk, tid, muy, s2);
  __syncthreads();
  // fold means now so mux/muy/s2 die before phase 3
  float mxy[8], rden[8];
#pragma unroll
  for (int i = 0; i < 8; ++i) {
    float m2x = mux[i] * mux[i];
    float m2y = muy[i] * muy[i];
    mxy[i] = mux[i] * muy[i];
    rden[i] = rcp_fast(s2[i] - m2x - m2y + kC2);
    if (LAST)   // luminance folded straight into PIcs
      PIcs[i] *= fmaf(2.f, mxy[i], kC1) * rcp_fast(m2x + m2y + kC1);
  }
  hstream<R, (LAST ? 2 : 1)>(xtT, ytT, hb0, hb1, wk, tid);
  __syncthreads();
  float exy[8];
#pragma unroll
  for (int i = 0; i < 8; ++i) exy[i] = 0.f;
  vstream<R, LAST>(hb0, hb1, wk, tid, exy, gl1);  // gl1 accumulated in-place
  __syncthreads();
#pragma unroll
  for (int i = 0; i < 8; ++i)
    PIcs[i] *= fmaf(2.f, exy[i] - mxy[i], kC2) * rden[i];
}

// ---- extract 1D separable kernels: g[j] = mask[16][j] / sqrt(mask[16][16]) ----
__global__ void prep_k(const float* __restrict__ gm, float* __restrict__ w1d) {
  int t = threadIdx.x;
  if (t < 165) {
    int s = t / 33, j = t % 33;
    const float* m = gm + (3 * s) * (33 * 33);
    float g16 = sqrtf(m[16 * 33 + 16]);
    w1d[t] = m[16 * 33 + j] / g16;
  }
}

__global__ __attribute__((amdgpu_flat_work_group_size(512, 512),
                          amdgpu_waves_per_eu(4, 4)))
void msloss_k(const float* __restrict__ x, const float* __restrict__ y,
              const float* __restrict__ w1d, float* __restrict__ out) {
  __shared__ __half xtT[96 * P1];   // transposed: xtT[col][row]
  __shared__ __half ytT[96 * P1];
  __shared__ __half hb0[96 * P2];   // hb[row][col]
  __shared__ __half hb1[96 * P2];
  __shared__ float red[8];
  const int tid = threadIdx.x;
  const int ox = blockIdx.x * TW, oy = blockIdx.y * TH;
  const int b = blockIdx.z;

  float PIcs[8], gl1[8];
#pragma unroll
  for (int i = 0; i < 8; ++i) { PIcs[i] = 1.f; gl1[i] = 0.f; }

  for (int c = 0; c < 3; ++c) {
    const float* xp = x + (size_t)(b * 3 + c) * (512 * 512);
    const float* yp = y + (size_t)(b * 3 + c) * (512 * 512);
    // stage 96x96 fp32 -> fp16 TRANSPOSED, zero halo; 4608 float2 slots
#pragma unroll
    for (int it = 0; it < 9; ++it) {
      int idx = it * 512 + tid;           // 96 rows x 48 colpairs
      int row = idx / 48, cp = idx % 48;
      int gy = oy + row - 16, gx = ox + cp * 2 - 16;
      bool ok = ((unsigned)gy < 512u) && ((unsigned)gx < 512u);  // gx even
      float2 xv = make_float2(0.f, 0.f), yv = make_float2(0.f, 0.f);
      if (ok) {
        xv = *reinterpret_cast<const float2*>(xp + gy * 512 + gx);
        yv = *reinterpret_cast<const float2*>(yp + gy * 512 + gx);
      }
      xtT[(cp * 2 + 0) * P1 + row] = __float2half_rn(xv.x);
      xtT[(cp * 2 + 1) * P1 + row] = __float2half_rn(xv.y);
      ytT[(cp * 2 + 0) * P1 + row] = __float2half_rn(yv.x);
      ytT[(cp * 2 + 1) * P1 + row] = __float2half_rn(yv.y);
    }
    __syncthreads();
    do_sigma<4,  false>(0, w1d, xtT, ytT, hb0, hb1, PIcs, gl1, tid);
    do_sigma<6,  false>(1, w1d, xtT, ytT, hb0, hb1, PIcs, gl1, tid);
    do_sigma<12, false>(2, w1d, xtT, ytT, hb0, hb1, PIcs, gl1, tid);
    do_sigma<16, false>(3, w1d, xtT, ytT, hb0, hb1, PIcs, gl1, tid);
    do_sigma<16, true >(4, w1d, xtT, ytT, hb0, hb1, PIcs, gl1, tid);
    // do_sigma ends with __syncthreads(): safe to restage next channel
  }

  float s = 0.f;
#pragma unroll
  for (int i = 0; i < 8; ++i)
    s += kALPHA * (1.f - PIcs[i]) + ((1.f - kALPHA) / 3.f) * gl1[i];
#pragma unroll
  for (int off = 32; off > 0; off >>= 1) s += __shfl_down(s, off);
  if ((tid & 63) == 0) red[tid >> 6] = s;
  __syncthreads();
  if (tid == 0) {
    float t = 0.f;
#pragma unroll
    for (int i = 0; i < 8; ++i) t += red[i];
    atomicAdd(out, t * (200.0f / (8.0f * 512.0f * 512.0f)));
  }
}

extern "C" void kernel_launch(void* const* d_in, const int* in_sizes, int n_in,
                              void* d_out, int out_size, void* d_ws, size_t ws_size,
                              hipStream_t stream) {
  const float* x = (const float*)d_in[0];
  const float* y = (const float*)d_in[1];
  const float* gm = (const float*)d_in[2];
  float* out = (float*)d_out;
  float* w1d = (float*)d_ws;  // 165 floats of 1D kernels

  hipMemsetAsync(d_out, 0, out_size * sizeof(float), stream);
  prep_k<<<1, 256, 0, stream>>>(gm, w1d);
  msloss_k<<<dim3(8, 8, 8), 512, 0, stream>>>(x, y, w1d, out);
}

// Round 6
// 780.509 us; speedup vs baseline: 1.2340x; 1.0092x over previous
//
#include <hip/hip_runtime.h>
#include <hip/hip_fp16.h>

#define DI __device__ __forceinline__

constexpr int TW = 64, TH = 64;      // output tile
constexpr int P1 = 98;               // x/y tile pitch (halfs), layout [col][row]
constexpr int P2 = 66;               // hb pitch (halfs), layout [row][col]
constexpr int TILE_H = 96 * P1;      // halfs per staged tile   (9408 -> +18816 B)
constexpr int HB_H   = 96 * P2;      // halfs per hb map        (6336 -> +12672 B)
constexpr float kC1 = 1.0e-4f;       // (0.01*1)^2
constexpr float kC2 = 9.0e-4f;       // (0.03*1)^2
constexpr float kALPHA = 0.025f;

DI float rcp_fast(float v) { return __builtin_amdgcn_rcpf(v); }

DI void ld2h(const __half* __restrict__ s, float& f0, float& f1) {
  unsigned u = *reinterpret_cast<const unsigned*>(s);
  __half2 h = *reinterpret_cast<__half2*>(&u);
  f0 = __low2float(h); f1 = __high2float(h);
}

DI void st2h(__half* __restrict__ d, float a0, float a1) {
  __half2 p = __floats2half2_rn(a0, a1);
  *reinterpret_cast<unsigned*>(d) = *reinterpret_cast<unsigned*>(&p);
}

// ---- horizontal conv over transposed tile; patch = 2 cols x 2 rows ----
// Marching pointer (p += P1 per tap); paired tile via +TILE_H immediate.
// MODE 0: h0=conv(v), h1=conv(v^2) from src.
// MODE 1: h0=conv(x*y).  MODE 2: h0=conv(x*y), h1=conv(|x-y|)  (src=xt).
template<int R, int MODE>
DI void hstream(const __half* __restrict__ src, __half* __restrict__ hb,
                const float* __restrict__ wk, int tid) {
  constexpr int K = 2 * R + 1;
  constexpr int NP = 32 * (32 + R);        // 32 colpairs x (32+R) rowpairs
  for (int s = tid; s < NP; s += 512) {
    const int cg = s & 31, rg = s >> 5;
    const int c0 = cg * 2, r0 = (16 - R) + rg * 2;
    const __half* p = src + (c0 + 16 - R) * P1 + r0;
    float a00 = 0, a01 = 0, a10 = 0, a11 = 0;
    float b00 = 0, b01 = 0, b10 = 0, b11 = 0;
#pragma unroll 2
    for (int t = 0; t < K + 1; ++t) {
      float x0, x1;
      ld2h(p, x0, x1);
      float p0, p1, d0 = 0.f, d1 = 0.f;
      if (MODE == 0) {
        p0 = x0 * x0; p1 = x1 * x1;
      } else {
        float y0, y1;
        ld2h(p + TILE_H, y0, y1);          // y tile at compile-time offset
        p0 = x0 * y0; p1 = x1 * y1;
        if (MODE == 2) { d0 = fabsf(x0 - y0); d1 = fabsf(x1 - y1); }
      }
      p += P1;
      if (t < K) {                          // col c0, tap j = t (uniform branch)
        const float w = wk[t];
        if (MODE == 0) {
          a00 = fmaf(w, x0, a00); a01 = fmaf(w, x1, a01);
          b00 = fmaf(w, p0, b00); b01 = fmaf(w, p1, b01);
        } else {
          a00 = fmaf(w, p0, a00); a01 = fmaf(w, p1, a01);
          if (MODE == 2) { b00 = fmaf(w, d0, b00); b01 = fmaf(w, d1, b01); }
        }
      }
      if (t >= 1) {                         // col c0+1, tap j = t-1
        const float w = wk[t - 1];
        if (MODE == 0) {
          a10 = fmaf(w, x0, a10); a11 = fmaf(w, x1, a11);
          b10 = fmaf(w, p0, b10); b11 = fmaf(w, p1, b11);
        } else {
          a10 = fmaf(w, p0, a10); a11 = fmaf(w, p1, a11);
          if (MODE == 2) { b10 = fmaf(w, d0, b10); b11 = fmaf(w, d1, b11); }
        }
      }
    }
    __half* wp = hb + r0 * P2 + c0;
    st2h(wp, a00, a10);
    st2h(wp + P2, a01, a11);
    if (MODE == 0 || MODE == 2) {
      st2h(wp + HB_H, b00, b10);            // 2nd map at immediate offset
      st2h(wp + HB_H + P2, b01, b11);
    }
  }
}

// ---- vertical conv: patch = 4 rows x 2 cols, exactly 1 patch/thread ----
template<int R, bool TWO>
DI void vstream(const __half* __restrict__ hb, const float* __restrict__ wk,
                int tid, float* __restrict__ acc0, float* __restrict__ acc1) {
  constexpr int K = 2 * R + 1;
  const int cg = tid & 31, rq = tid >> 5;
  const int c0 = cg * 2, r0 = rq * 4;
  const __half* p = hb + (r0 + 16 - R) * P2 + c0;
#pragma unroll 2
  for (int t = 0; t < K + 3; ++t) {
    float x0, x1;
    ld2h(p, x0, x1);
    float y0 = 0.f, y1 = 0.f;
    if (TWO) ld2h(p + HB_H, y0, y1);
    p += P2;
#pragma unroll
    for (int rr = 0; rr < 4; ++rr) {
      const int j = t - rr;
      if (j >= 0 && j < K) {
        const float w = wk[j];
        acc0[rr * 2 + 0] = fmaf(w, x0, acc0[rr * 2 + 0]);
        acc0[rr * 2 + 1] = fmaf(w, x1, acc0[rr * 2 + 1]);
        if (TWO) {
          acc1[rr * 2 + 0] = fmaf(w, y0, acc1[rr * 2 + 0]);
          acc1[rr * 2 + 1] = fmaf(w, y1, acc1[rr * 2 + 1]);
        }
      }
    }
  }
}

// Phase-pipelined per-sigma. Per-thread arrays 8-wide; gl1 is a SCALAR
// (linear in pixels -> collapse immediately). Worst-phase liveness ~55 regs.
template<int R, bool LAST>
DI void do_sigma(int sidx, const float* __restrict__ w1d,
                 const __half* __restrict__ xt, __half* __restrict__ hb,
                 float* __restrict__ PIcs, float& gl1s, int tid) {
  const float* wk = w1d + sidx * 33 + (16 - R);
  float mux[8], muy[8], s2[8];             // s2 = E[x^2]+E[y^2] merged
#pragma unroll
  for (int i = 0; i < 8; ++i) { mux[i] = 0.f; s2[i] = 0.f; }
  hstream<R, 0>(xt, hb, wk, tid);          // x, x^2
  __syncthreads();
  vstream<R, true>(hb, wk, tid, mux, s2);
  __syncthreads();
  hstream<R, 0>(xt + TILE_H, hb, wk, tid); // y, y^2
  __syncthreads();
#pragma unroll
  for (int i = 0; i < 8; ++i) muy[i] = 0.f;
  vstream<R, true>(hb, wk, tid, muy, s2);
  __syncthreads();
  // fold means now so mux/muy/s2 die before phase 3
  float mxy[8], rden[8];
#pragma unroll
  for (int i = 0; i < 8; ++i) {
    float m2x = mux[i] * mux[i];
    float m2y = muy[i] * muy[i];
    mxy[i] = mux[i] * muy[i];
    rden[i] = rcp_fast(s2[i] - m2x - m2y + kC2);
    if (LAST)   // luminance folded straight into PIcs
      PIcs[i] *= fmaf(2.f, mxy[i], kC1) * rcp_fast(m2x + m2y + kC1);
  }
  hstream<R, (LAST ? 2 : 1)>(xt, hb, wk, tid);   // x*y (, |x-y|)
  __syncthreads();
  float exy[8], l1[8];
#pragma unroll
  for (int i = 0; i < 8; ++i) { exy[i] = 0.f; l1[i] = 0.f; }
  vstream<R, LAST>(hb, wk, tid, exy, l1);
  __syncthreads();
#pragma unroll
  for (int i = 0; i < 8; ++i) {
    PIcs[i] *= fmaf(2.f, exy[i] - mxy[i], kC2) * rden[i];
    if (LAST) gl1s += l1[i];
  }
}

// ---- extract 1D separable kernels: g[j] = mask[16][j] / sqrt(mask[16][16]) ----
__global__ void prep_k(const float* __restrict__ gm, float* __restrict__ w1d) {
  int t = threadIdx.x;
  if (t < 165) {
    int s = t / 33, j = t % 33;
    const float* m = gm + (3 * s) * (33 * 33);
    float g16 = sqrtf(m[16 * 33 + 16]);
    w1d[t] = m[16 * 33 + j] / g16;
  }
}

// __launch_bounds__(512,4): min 4 waves/EU -> 128-VGPR budget (canonical HIP
// lowering; raw amdgpu_* attrs were ignored R1-R5: allocator always picked
// 4-workgroups/CU sizing and spilled 197-831 MB of scratch).
__global__ __launch_bounds__(512, 4)
void msloss_k(const float* __restrict__ x, const float* __restrict__ y,
              const float* __restrict__ w1d, float* __restrict__ out) {
  // one block so paired buffers sit at compile-time ds offsets:
  // xt @0, yt @TILE_H, hb0 @2*TILE_H, hb1 @2*TILE_H+HB_H
  __shared__ __half smem[2 * TILE_H + 2 * HB_H];
  __shared__ float red[8];
  __half* xt = smem;
  __half* yt = smem + TILE_H;
  __half* hb = smem + 2 * TILE_H;
  const int tid = threadIdx.x;
  const int ox = blockIdx.x * TW, oy = blockIdx.y * TH;
  const int b = blockIdx.z;

  float PIcs[8];
  float gl1s = 0.f;
#pragma unroll
  for (int i = 0; i < 8; ++i) PIcs[i] = 1.f;

  for (int c = 0; c < 3; ++c) {
    const float* xp = x + (size_t)(b * 3 + c) * (512 * 512);
    const float* yp = y + (size_t)(b * 3 + c) * (512 * 512);
    // stage 96x96 fp32 -> fp16 TRANSPOSED, zero halo; 4608 float2 slots
#pragma unroll
    for (int it = 0; it < 9; ++it) {
      int idx = it * 512 + tid;           // 96 rows x 48 colpairs
      int row = idx / 48, cp = idx % 48;
      int gy = oy + row - 16, gx = ox + cp * 2 - 16;
      bool ok = ((unsigned)gy < 512u) && ((unsigned)gx < 512u);  // gx even
      float2 xv = make_float2(0.f, 0.f), yv = make_float2(0.f, 0.f);
      if (ok) {
        xv = *reinterpret_cast<const float2*>(xp + gy * 512 + gx);
        yv = *reinterpret_cast<const float2*>(yp + gy * 512 + gx);
      }
      __half* px = xt + (cp * 2) * P1 + row;
      px[0] = __float2half_rn(xv.x);
      px[P1] = __float2half_rn(xv.y);
      px[TILE_H] = __float2half_rn(yv.x);          // yt at immediate offset
      px[TILE_H + P1] = __float2half_rn(yv.y);
    }
    __syncthreads();
    do_sigma<4,  false>(0, w1d, xt, hb, PIcs, gl1s, tid);
    do_sigma<6,  false>(1, w1d, xt, hb, PIcs, gl1s, tid);
    do_sigma<12, false>(2, w1d, xt, hb, PIcs, gl1s, tid);
    do_sigma<16, false>(3, w1d, xt, hb, PIcs, gl1s, tid);
    do_sigma<16, true >(4, w1d, xt, hb, PIcs, gl1s, tid);
    // do_sigma ends with __syncthreads(): safe to restage next channel
  }

  float s = ((1.f - kALPHA) / 3.f) * gl1s;
#pragma unroll
  for (int i = 0; i < 8; ++i) s += kALPHA * (1.f - PIcs[i]);
#pragma unroll
  for (int off = 32; off > 0; off >>= 1) s += __shfl_down(s, off);
  if ((tid & 63) == 0) red[tid >> 6] = s;
  __syncthreads();
  if (tid == 0) {
    float t = 0.f;
#pragma unroll
    for (int i = 0; i < 8; ++i) t += red[i];
    atomicAdd(out, t * (200.0f / (8.0f * 512.0f * 512.0f)));
  }
}

extern "C" void kernel_launch(void* const* d_in, const int* in_sizes, int n_in,
                              void* d_out, int out_size, void* d_ws, size_t ws_size,
                              hipStream_t stream) {
  const float* x = (const float*)d_in[0];
  const float* y = (const float*)d_in[1];
  const float* gm = (const float*)d_in[2];
  float* out = (float*)d_out;
  float* w1d = (float*)d_ws;  // 165 floats of 1D kernels

  hipMemsetAsync(d_out, 0, out_size * sizeof(float), stream);
  prep_k<<<1, 256, 0, stream>>>(gm, w1d);
  msloss_k<<<dim3(8, 8, 8), 512, 0, stream>>>(x, y, w1d, out);
}

// Round 8
// 662.816 us; speedup vs baseline: 1.4531x; 1.1776x over previous
//
#include <hip/hip_runtime.h>
#include <hip/hip_fp16.h>

#define DI __device__ __forceinline__

constexpr int TW = 64, TH = 64;      // output tile
constexpr int P1 = 98;               // x/y tile pitch (halfs), layout [col][row]
constexpr int P2 = 66;               // hb pitch (halfs), layout [row][col]
constexpr int TILE_H = 96 * P1;      // halfs per staged tile
constexpr int HB_H   = 96 * P2;      // halfs per hb map
constexpr float kC1 = 1.0e-4f;       // (0.01*1)^2
constexpr float kC2 = 9.0e-4f;       // (0.03*1)^2
constexpr float kALPHA = 0.025f;

DI float rcp_fast(float v) { return __builtin_amdgcn_rcpf(v); }

DI void ld2h(const __half* __restrict__ s, float& f0, float& f1) {
  unsigned u = *reinterpret_cast<const unsigned*>(s);
  __half2 h = *reinterpret_cast<__half2*>(&u);
  f0 = __low2float(h); f1 = __high2float(h);
}

DI void st2h(__half* __restrict__ d, float a0, float a1) {
  __half2 p = __floats2half2_rn(a0, a1);
  *reinterpret_cast<unsigned*>(d) = *reinterpret_cast<unsigned*>(&p);
}

// ---- horizontal conv over transposed tile; patch = 2 cols x 2 rows ----
// Tap loop FULLY unrolled: every ds_read offset is a compile-time immediate
// off one base VGPR; wk[t] are uniform scalar loads; guards fold away.
// MODE 0: hb0=conv(v), hb1=conv(v^2) from src.
// MODE 1: hb0=conv(x*y).  MODE 2: hb0=conv(x*y), hb1=conv(|x-y|).
template<int R, int MODE>
DI void hstream(const __half* __restrict__ src, __half* __restrict__ hb,
                const float* __restrict__ wk, int tid) {
  constexpr int K = 2 * R + 1;
  constexpr int NP = 32 * (32 + R);        // 32 colpairs x (32+R) rowpairs
  for (int s = tid; s < NP; s += 256) {
    const int cg = s & 31, rg = s >> 5;
    const int c0 = cg * 2, r0 = (16 - R) + rg * 2;
    const __half* p = src + (c0 + 16 - R) * P1 + r0;
    float a00 = 0, a01 = 0, a10 = 0, a11 = 0;
    float b00 = 0, b01 = 0, b10 = 0, b11 = 0;
#pragma unroll
    for (int t = 0; t < K + 1; ++t) {
      float x0, x1;
      ld2h(p + t * P1, x0, x1);            // immediate offset
      float q0, q1, d0 = 0.f, d1 = 0.f;
      if (MODE == 0) {
        q0 = x0 * x0; q1 = x1 * x1;
      } else {
        float y0, y1;
        ld2h(p + t * P1 + TILE_H, y0, y1); // y tile at immediate offset
        q0 = x0 * y0; q1 = x1 * y1;
        if (MODE == 2) { d0 = fabsf(x0 - y0); d1 = fabsf(x1 - y1); }
      }
      if (t < K) {                          // compile-time after unroll
        const float w = wk[t];
        if (MODE == 0) {
          a00 = fmaf(w, x0, a00); a01 = fmaf(w, x1, a01);
          b00 = fmaf(w, q0, b00); b01 = fmaf(w, q1, b01);
        } else {
          a00 = fmaf(w, q0, a00); a01 = fmaf(w, q1, a01);
          if (MODE == 2) { b00 = fmaf(w, d0, b00); b01 = fmaf(w, d1, b01); }
        }
      }
      if (t >= 1) {
        const float w = wk[t - 1];
        if (MODE == 0) {
          a10 = fmaf(w, x0, a10); a11 = fmaf(w, x1, a11);
          b10 = fmaf(w, q0, b10); b11 = fmaf(w, q1, b11);
        } else {
          a10 = fmaf(w, q0, a10); a11 = fmaf(w, q1, a11);
          if (MODE == 2) { b10 = fmaf(w, d0, b10); b11 = fmaf(w, d1, b11); }
        }
      }
    }
    __half* wp = hb + r0 * P2 + c0;
    st2h(wp, a00, a10);
    st2h(wp + P2, a01, a11);
    if (MODE == 0 || MODE == 2) {
      st2h(wp + HB_H, b00, b10);
      st2h(wp + HB_H + P2, b01, b11);
    }
  }
}

// ---- vertical conv, ONE map, patch = 8 rows x 2 cols (16 outputs) ----
// dword addr = 33*lr + cg with cg spanning all 32 banks -> <=2-way (free).
template<int R>
DI void vstream1(const __half* __restrict__ hb, const float* __restrict__ wk,
                 int tid, float* __restrict__ acc) {
  constexpr int K = 2 * R + 1;
  const int cg = tid & 31, rq = tid >> 5;
  const __half* p = hb + (8 * rq + 16 - R) * P2 + 2 * cg;
#pragma unroll
  for (int t = 0; t < K + 7; ++t) {
    float x0, x1;
    ld2h(p + t * P2, x0, x1);              // immediate offset
#pragma unroll
    for (int rr = 0; rr < 8; ++rr) {
      const int j = t - rr;
      if (j >= 0 && j < K) {               // folds at compile time
        const float w = wk[j];
        acc[rr * 2 + 0] = fmaf(w, x0, acc[rr * 2 + 0]);
        acc[rr * 2 + 1] = fmaf(w, x1, acc[rr * 2 + 1]);
      }
    }
  }
}

// ---- vertical conv of |x-y| map collapsed to a SCALAR ----
// sum over this thread's 16 pixels is linear: per t-step the load carries a
// uniform weight W(t) = sum of valid wk[t-rr] -> 1 register, 2 fma per step.
template<int R>
DI float vstream_l1(const __half* __restrict__ hb, const float* __restrict__ wk,
                    int tid) {
  constexpr int K = 2 * R + 1;
  const int cg = tid & 31, rq = tid >> 5;
  const __half* p = hb + (8 * rq + 16 - R) * P2 + 2 * cg;
  float s = 0.f;
#pragma unroll
  for (int t = 0; t < K + 7; ++t) {
    float W = 0.f;                          // uniform: compiler keeps in SGPRs
#pragma unroll
    for (int rr = 0; rr < 8; ++rr) {
      const int j = t - rr;
      if (j >= 0 && j < K) W += wk[j];
    }
    float x0, x1;
    ld2h(p + t * P2, x0, x1);
    s = fmaf(W, x0 + x1, s);
  }
  return s;
}

// Per-sigma pipeline with single-map v-passes; worst-phase liveness ~81 regs
// (PIcs 16 + mxy 16 + rden 16 + acc 16 + working) vs the observed hard
// 128-reg budget at 256 threads (VGPR_Count*threads == 32768 in R0-R6).
template<int R, bool LAST>
DI void do_sigma(int sidx, const float* __restrict__ w1d,
                 const __half* __restrict__ xt, __half* __restrict__ hb,
                 float* __restrict__ PIcs, float& gl1s, int tid) {
  const float* wk = w1d + sidx * 33 + (16 - R);
  float mux[16], muy[16], s2[16];
#pragma unroll
  for (int i = 0; i < 16; ++i) { mux[i] = 0.f; s2[i] = 0.f; }
  hstream<R, 0>(xt, hb, wk, tid);          // hb0 = h(x), hb1 = h(x^2)
  __syncthreads();
  vstream1<R>(hb, wk, tid, mux);
  vstream1<R>(hb + HB_H, wk, tid, s2);     // hb1 = h(x^2)  [R7 bug: was +2*HB_H, OOB]
  __syncthreads();
  hstream<R, 0>(xt + TILE_H, hb, wk, tid); // hb0 = h(y), hb1 = h(y^2)
  __syncthreads();
#pragma unroll
  for (int i = 0; i < 16; ++i) muy[i] = 0.f;
  vstream1<R>(hb, wk, tid, muy);
  vstream1<R>(hb + HB_H, wk, tid, s2);     // accumulate E[x^2]+E[y^2]
  __syncthreads();
  // fold in place: mux <- mxy, muy <- rden; mux/muy/s2 die here
#pragma unroll
  for (int i = 0; i < 16; ++i) {
    float a = mux[i], b = muy[i];
    float m2 = a * a + b * b;
    mux[i] = a * b;                        // mxy
    muy[i] = rcp_fast(s2[i] - m2 + kC2);   // rden
    if (LAST)                              // luminance folded into PIcs
      PIcs[i] *= fmaf(2.f, mux[i], kC1) * rcp_fast(m2 + kC1);
  }
  hstream<R, (LAST ? 2 : 1)>(xt, hb, wk, tid);   // hb0 = h(x*y) (, hb1=h(|d|))
  __syncthreads();
  float exy[16];
#pragma unroll
  for (int i = 0; i < 16; ++i) exy[i] = 0.f;
  vstream1<R>(hb, wk, tid, exy);
  if (LAST) gl1s += vstream_l1<R>(hb + HB_H, wk, tid);
  __syncthreads();
#pragma unroll
  for (int i = 0; i < 16; ++i)
    PIcs[i] *= fmaf(2.f, exy[i] - mux[i], kC2) * muy[i];
}

// ---- extract 1D separable kernels: g[j] = mask[16][j] / sqrt(mask[16][16]) ----
__global__ void prep_k(const float* __restrict__ gm, float* __restrict__ w1d) {
  int t = threadIdx.x;
  if (t < 165) {
    int s = t / 33, j = t % 33;
    const float* m = gm + (3 * s) * (33 * 33);
    float g16 = sqrtf(m[16 * 33 + 16]);
    w1d[t] = m[16 * 33 + j] / g16;
  }
}

__global__ __launch_bounds__(256)
void msloss_k(const float* __restrict__ x, const float* __restrict__ y,
              const float* __restrict__ w1d, float* __restrict__ out) {
  // xt @0, yt @TILE_H, hb0 @2*TILE_H, hb1 @2*TILE_H+HB_H (immediate offsets)
  __shared__ __half smem[2 * TILE_H + 2 * HB_H];
  __shared__ float red[4];
  __half* xt = smem;
  __half* hb = smem + 2 * TILE_H;
  const int tid = threadIdx.x;
  const int ox = blockIdx.x * TW, oy = blockIdx.y * TH;
  const int b = blockIdx.z;

  float PIcs[16];
  float gl1s = 0.f;
#pragma unroll
  for (int i = 0; i < 16; ++i) PIcs[i] = 1.f;

  for (int c = 0; c < 3; ++c) {
    const float* xp = x + (size_t)(b * 3 + c) * (512 * 512);
    const float* yp = y + (size_t)(b * 3 + c) * (512 * 512);
    // stage 96x96 fp32 -> fp16 TRANSPOSED (zero halo): 96 cols x 48 rowpairs
#pragma unroll
    for (int it = 0; it < 18; ++it) {
      int idx = it * 256 + tid;
      int rp = idx / 96, col = idx - rp * 96;
      int gx = ox + col - 16;
      int gy0 = oy + rp * 2 - 16;
      float x0 = 0.f, x1 = 0.f, y0 = 0.f, y1 = 0.f;
      if ((unsigned)gx < 512u) {
        if ((unsigned)gy0 < 512u)       { x0 = xp[gy0 * 512 + gx];       y0 = yp[gy0 * 512 + gx]; }
        if ((unsigned)(gy0 + 1) < 512u) { x1 = xp[(gy0 + 1) * 512 + gx]; y1 = yp[(gy0 + 1) * 512 + gx]; }
      }
      st2h(xt + col * P1 + rp * 2, x0, x1);
      st2h(xt + TILE_H + col * P1 + rp * 2, y0, y1);
    }
    __syncthreads();
    do_sigma<4,  false>(0, w1d, xt, hb, PIcs, gl1s, tid);
    do_sigma<6,  false>(1, w1d, xt, hb, PIcs, gl1s, tid);
    do_sigma<12, false>(2, w1d, xt, hb, PIcs, gl1s, tid);
    do_sigma<16, false>(3, w1d, xt, hb, PIcs, gl1s, tid);
    do_sigma<16, true >(4, w1d, xt, hb, PIcs, gl1s, tid);
    // do_sigma ends with __syncthreads(): safe to restage next channel
  }

  float s = ((1.f - kALPHA) / 3.f) * gl1s;
#pragma unroll
  for (int i = 0; i < 16; ++i) s += kALPHA * (1.f - PIcs[i]);
#pragma unroll
  for (int off = 32; off > 0; off >>= 1) s += __shfl_down(s, off);
  if ((tid & 63) == 0) red[tid >> 6] = s;
  __syncthreads();
  if (tid == 0)
    atomicAdd(out, (red[0] + red[1] + red[2] + red[3]) *
                       (200.0f / (8.0f * 512.0f * 512.0f)));
}

extern "C" void kernel_launch(void* const* d_in, const int* in_sizes, int n_in,
                              void* d_out, int out_size, void* d_ws, size_t ws_size,
                              hipStream_t stream) {
  const float* x = (const float*)d_in[0];
  const float* y = (const float*)d_in[1];
  const float* gm = (const float*)d_in[2];
  float* out = (float*)d_out;
  float* w1d = (float*)d_ws;  // 165 floats of 1D kernels

  hipMemsetAsync(d_out, 0, out_size * sizeof(float), stream);
  prep_k<<<1, 256, 0, stream>>>(gm, w1d);
  msloss_k<<<dim3(8, 8, 8), 256, 0, stream>>>(x, y, w1d, out);
}

// Round 9
// 574.865 us; speedup vs baseline: 1.6754x; 1.1530x over previous
//
#include <hip/hip_runtime.h>

typedef _Float16 h2_t __attribute__((ext_vector_type(2)));

#define DI __device__ __forceinline__

constexpr int PA = 98;           // pitch in halfs (49 dwords, odd -> bank spread)
constexpr int TILE = 96 * PA;    // halfs per staged x/y tile (9408)
constexpr int HBOFF = 64 * PA;   // halfs per hb map (6272)
constexpr float kC1 = 1.0e-4f;   // (0.01*1)^2
constexpr float kC2 = 9.0e-4f;   // (0.03*1)^2
constexpr float kALPHA = 0.025f;

DI float rcp_fast(float v) { return __builtin_amdgcn_rcpf(v); }

DI float fdot2f(h2_t a, h2_t b, float c) {
#if __has_builtin(__builtin_amdgcn_fdot2)
  return __builtin_amdgcn_fdot2(a, b, c, false);   // v_dot2_f32_f16
#else
  return c + (float)(a.x) * (float)(b.x) + (float)(a.y) * (float)(b.y);
#endif
}

DI h2_t ldh2(const _Float16* __restrict__ p) {
  return *reinterpret_cast<const h2_t*>(p);
}
DI h2_t w2h(unsigned u) { return __builtin_bit_cast(h2_t, u); }
DI h2_t pkabs(h2_t v) {
  unsigned u = __builtin_bit_cast(unsigned, v) & 0x7FFF7FFFu;
  return __builtin_bit_cast(h2_t, u);
}

// ---- horizontal conv: xt[row][col] -> hb[col][row] ----
// Group = 1 row x 8 stride-2 cols {c0,c0+2,..,c0+14}; window pairs are
// adjacent halfs -> fdot2 (2 taps/instr, 0 cvt). Weight table E (even c0)
// or O (odd c0) handles pair alignment. MODE 0: hb0=conv(v),hb1=conv(v^2);
// MODE 1: hb0=conv(x*y); MODE 2: hb0=conv(x*y), hb1=conv(|x-y|).
template<int R, int MODE>
DI void hconv(const _Float16* __restrict__ src, _Float16* __restrict__ hb,
              const unsigned* __restrict__ tabs, int tid) {
  constexpr int NR = 64 + 2 * R;           // rows produced: [16-R, 80+R)
  constexpr int NG = NR * 8;
  for (int g = tid; g < NG; g += 256) {
    const int row = (16 - R) + (g % NR);
    const int ci = g / NR;                 // 0..7
    const int c0 = ((ci >> 1) << 4) | (ci & 1);
    const int par = ci & 1;
    const unsigned* wt = tabs + (par ? 32 : 0);
    const int pbase = (c0 + 16 - R - par) >> 1;
    const _Float16* px = src + row * PA + 2 * pbase;
    float a[8], b[8];
#pragma unroll
    for (int i = 0; i < 8; ++i) { a[i] = 0.f; b[i] = 0.f; }
#pragma unroll
    for (int p = 0; p < R + 8; ++p) {
      h2_t xq = ldh2(px + 2 * p);
      h2_t q, d;
      if (MODE == 0) {
        q = xq * xq;                        // v_pk_mul_f16
      } else {
        h2_t yq = ldh2(px + 2 * p + TILE);  // y tile at immediate offset
        q = xq * yq;
        if (MODE == 2) d = pkabs(xq - yq);
      }
#pragma unroll
      for (int i = 0; i < 8; ++i) {
        const int j = p - i;
        if (j >= 0 && j <= R) {             // folds at compile time
          h2_t w = w2h(wt[j]);              // uniform -> SGPR
          if (MODE == 0) {
            a[i] = fdot2f(w, xq, a[i]);
            b[i] = fdot2f(w, q, b[i]);
          } else {
            a[i] = fdot2f(w, q, a[i]);
            if (MODE == 2) b[i] = fdot2f(w, d, b[i]);
          }
        }
      }
    }
    _Float16* wp = hb + c0 * PA + row;      // hb[col][row]
#pragma unroll
    for (int i = 0; i < 8; ++i) {
      wp[i * (2 * PA)] = (_Float16)a[i];
      if (MODE != 1) wp[i * (2 * PA) + HBOFF] = (_Float16)b[i];
    }
  }
}

// ---- vertical conv: hb[col][row], row-pairs adjacent -> fdot2 ----
// Thread: cols {cg, cg+32} x 8 stride-2 rows {r0,r0+2,..,r0+14}; 16 outputs.
template<int R>
DI void vconv(const _Float16* __restrict__ hcol, const unsigned* __restrict__ wt,
              int cg, int pbase, float* __restrict__ acc) {
  const _Float16* pA = hcol + cg * PA + 2 * pbase;
#pragma unroll
  for (int p = 0; p < R + 8; ++p) {
    h2_t va = ldh2(pA + 2 * p);
    h2_t vb = ldh2(pA + 2 * p + 32 * PA);
#pragma unroll
    for (int m = 0; m < 8; ++m) {
      const int j = p - m;
      if (j >= 0 && j <= R) {
        h2_t w = w2h(wt[j]);
        acc[2 * m + 0] = fdot2f(w, va, acc[2 * m + 0]);
        acc[2 * m + 1] = fdot2f(w, vb, acc[2 * m + 1]);
      }
    }
  }
}

// ---- vertical conv of |x-y| collapsed to a scalar via uniform U table ----
template<int R>
DI float vl1(const _Float16* __restrict__ hcol, const unsigned* __restrict__ Ut,
             int cg, int pbase) {
  const _Float16* pA = hcol + cg * PA + 2 * pbase;
  float s = 0.f;
#pragma unroll
  for (int p = 0; p < R + 8; ++p) {
    h2_t u = ldh2(pA + 2 * p) + ldh2(pA + 2 * p + 32 * PA);  // v_pk_add_f16
    s = fdot2f(w2h(Ut[p]), u, s);
  }
  return s;
}

template<int R, bool LAST>
DI void do_sigma(int sidx, const unsigned* __restrict__ tabs0,
                 const _Float16* __restrict__ xt, _Float16* __restrict__ hb,
                 float* __restrict__ PIcs, float& gl1s, int tid) {
  const unsigned* tabs = tabs0 + sidx * 64;
  const int cg = tid & 31, rq = tid >> 5;
  const int r0 = ((rq >> 1) << 4) | (rq & 1);
  const int par = rq & 1;
  const unsigned* wt = tabs + (par ? 32 : 0);
  const int pbase = (r0 + 16 - R - par) >> 1;

  float mux[16], muy[16], s2[16];
#pragma unroll
  for (int i = 0; i < 16; ++i) { mux[i] = 0.f; s2[i] = 0.f; }
  hconv<R, 0>(xt, hb, tabs, tid);          // hb0=h(x), hb1=h(x^2)
  __syncthreads();
  vconv<R>(hb, wt, cg, pbase, mux);
  vconv<R>(hb + HBOFF, wt, cg, pbase, s2);
  __syncthreads();
  hconv<R, 0>(xt + TILE, hb, tabs, tid);   // hb0=h(y), hb1=h(y^2)
  __syncthreads();
#pragma unroll
  for (int i = 0; i < 16; ++i) muy[i] = 0.f;
  vconv<R>(hb, wt, cg, pbase, muy);
  vconv<R>(hb + HBOFF, wt, cg, pbase, s2); // E[x^2]+E[y^2]
  __syncthreads();
  // fold in place: mux <- mxy, muy <- rden; mux/muy/s2 die here
#pragma unroll
  for (int i = 0; i < 16; ++i) {
    float a = mux[i], b = muy[i];
    float m2 = a * a + b * b;
    mux[i] = a * b;                        // mxy
    muy[i] = rcp_fast(s2[i] - m2 + kC2);   // rden
    if (LAST)                              // luminance folded into PIcs
      PIcs[i] *= fmaf(2.f, mux[i], kC1) * rcp_fast(m2 + kC1);
  }
  hconv<R, (LAST ? 2 : 1)>(xt, hb, tabs, tid);  // hb0=h(xy) (, hb1=h(|d|))
  __syncthreads();
  float exy[16];
#pragma unroll
  for (int i = 0; i < 16; ++i) exy[i] = 0.f;
  vconv<R>(hb, wt, cg, pbase, exy);
  if (LAST)
    gl1s += vl1<R>(hb + HBOFF, tabs0 + 320 + (par ? 24 : 0), cg, pbase);
  __syncthreads();
#pragma unroll
  for (int i = 0; i < 16; ++i)
    PIcs[i] *= fmaf(2.f, exy[i] - mux[i], kC2) * muy[i];
}

DI unsigned packh(float a, float b) {
  h2_t v; v.x = (_Float16)a; v.y = (_Float16)b;
  return __builtin_bit_cast(unsigned, v);
}

// ws layout: [0..164] fp32 1D kernels; then u32 tabs: per sigma s (5):
// E pairs at s*64+[0..R], O pairs at s*64+32+[0..R]; U tables (l1, R=16):
// U_even at 320+[0..23], U_odd at 344+[0..23].
__global__ void prep_k(const float* __restrict__ gm, float* __restrict__ ws) {
  int t = threadIdx.x;
  if (t < 165) {
    int s = t / 33, j = t % 33;
    const float* m = gm + (3 * s) * (33 * 33);
    ws[t] = m[16 * 33 + j] / sqrtf(m[16 * 33 + 16]);
  }
  __syncthreads();
  if (t == 0) {
    unsigned* tabs = (unsigned*)(ws + 165);
    const int Rs[5] = {4, 6, 12, 16, 16};
    for (int s = 0; s < 5; ++s) {
      const int R = Rs[s];
      const float* w = ws + s * 33 + (16 - R);   // K = 2R+1 taps
      unsigned* E = tabs + s * 64;
      unsigned* O = E + 32;
      for (int i = 0; i < R; ++i) E[i] = packh(w[2 * i], w[2 * i + 1]);
      E[R] = packh(w[2 * R], 0.f);
      O[0] = packh(0.f, w[0]);
      for (int i = 1; i <= R; ++i) O[i] = packh(w[2 * i - 1], w[2 * i]);
    }
    // l1 collapse tables (sigma idx 4, R=16, K=33, window offset 0)
    const float* w = ws + 4 * 33;
    unsigned* UE = tabs + 320;
    unsigned* UO = tabs + 344;
    for (int p = 0; p < 24; ++p) {
      float ex = 0, ey = 0, ox = 0, oy = 0;
      for (int m = 0; m < 8; ++m) {
        int j = 2 * p - 2 * m;
        if (j >= 0 && j < 33) { ex += w[j]; oy += w[j]; }
        j = 2 * p + 1 - 2 * m;
        if (j >= 0 && j < 33) ey += w[j];
        j = 2 * p - 1 - 2 * m;
        if (j >= 0 && j < 33) ox += w[j];
      }
      UE[p] = packh(ex, ey);
      UO[p] = packh(ox, oy);
    }
  }
}

__global__ __launch_bounds__(256)
void msloss_k(const float* __restrict__ x, const float* __restrict__ y,
              const float* __restrict__ ws, float* __restrict__ out) {
  // xt @0 [row][col], yt @TILE, hb0 @2*TILE [col][row], hb1 @2*TILE+HBOFF
  __shared__ __align__(16) _Float16 smem[2 * TILE + 2 * HBOFF];
  __shared__ float red[4];
  _Float16* xt = smem;
  _Float16* hb = smem + 2 * TILE;
  const unsigned* tabs0 = (const unsigned*)(ws + 165);
  const int tid = threadIdx.x;
  const int ox = blockIdx.x * 64, oy = blockIdx.y * 64;
  const int b = blockIdx.z;

  float PIcs[16];
  float gl1s = 0.f;
#pragma unroll
  for (int i = 0; i < 16; ++i) PIcs[i] = 1.f;

  for (int c = 0; c < 3; ++c) {
    const float* xp = x + (size_t)(b * 3 + c) * (512 * 512);
    const float* yp = y + (size_t)(b * 3 + c) * (512 * 512);
    // stage 96x96 fp32 -> fp16, NATURAL [row][col], zero halo
#pragma unroll
    for (int it = 0; it < 18; ++it) {
      int idx = it * 256 + tid;            // 96 rows x 48 colpairs
      int row = idx / 48, cp = idx % 48;
      int gy = oy + row - 16, gx = ox + cp * 2 - 16;
      bool ok = ((unsigned)gy < 512u) && ((unsigned)gx < 512u);  // gx even
      float2 xv = make_float2(0.f, 0.f), yv = make_float2(0.f, 0.f);
      if (ok) {
        xv = *reinterpret_cast<const float2*>(xp + gy * 512 + gx);
        yv = *reinterpret_cast<const float2*>(yp + gy * 512 + gx);
      }
      h2_t hx; hx.x = (_Float16)xv.x; hx.y = (_Float16)xv.y;
      h2_t hy; hy.x = (_Float16)yv.x; hy.y = (_Float16)yv.y;
      *reinterpret_cast<h2_t*>(xt + row * PA + cp * 2) = hx;
      *reinterpret_cast<h2_t*>(xt + TILE + row * PA + cp * 2) = hy;
    }
    __syncthreads();
    do_sigma<4,  false>(0, tabs0, xt, hb, PIcs, gl1s, tid);
    do_sigma<6,  false>(1, tabs0, xt, hb, PIcs, gl1s, tid);
    do_sigma<12, false>(2, tabs0, xt, hb, PIcs, gl1s, tid);
    do_sigma<16, false>(3, tabs0, xt, hb, PIcs, gl1s, tid);
    do_sigma<16, true >(4, tabs0, xt, hb, PIcs, gl1s, tid);
    // do_sigma ends with __syncthreads(): safe to restage next channel
  }

  float s = ((1.f - kALPHA) / 3.f) * gl1s;
#pragma unroll
  for (int i = 0; i < 16; ++i) s += kALPHA * (1.f - PIcs[i]);
#pragma unroll
  for (int off = 32; off > 0; off >>= 1) s += __shfl_down(s, off);
  if ((tid & 63) == 0) red[tid >> 6] = s;
  __syncthreads();
  if (tid == 0)
    atomicAdd(out, (red[0] + red[1] + red[2] + red[3]) *
                       (200.0f / (8.0f * 512.0f * 512.0f)));
}

extern "C" void kernel_launch(void* const* d_in, const int* in_sizes, int n_in,
                              void* d_out, int out_size, void* d_ws, size_t ws_size,
                              hipStream_t stream) {
  const float* x = (const float*)d_in[0];
  const float* y = (const float*)d_in[1];
  const float* gm = (const float*)d_in[2];
  float* out = (float*)d_out;
  float* ws = (float*)d_ws;   // 165 f32 + packed half2 tables (~2 KB)

  hipMemsetAsync(d_out, 0, out_size * sizeof(float), stream);
  prep_k<<<1, 256, 0, stream>>>(gm, ws);
  msloss_k<<<dim3(8, 8, 8), 256, 0, stream>>>(x, y, ws, out);
}